// Round 4
// baseline (1005.996 us; speedup 1.0000x reference)
//
#include <hip/hip_runtime.h>

#define BB 8
#define HH 512
#define WW 1024
#define TILE 32
#define HALO 2
#define LW (TILE + 2*HALO)   // 36

__device__ __forceinline__ float sigm(float v) { return 1.0f / (1.0f + __expf(-v)); }

// load (row[x0], row[x0+1]) with x clamped to [0, W-1]
__device__ __forceinline__ float2 ld2c(const float* __restrict__ row, int x0) {
    if ((unsigned)x0 < (unsigned)(WW - 1)) {
        return *reinterpret_cast<const float2*>(row + x0);
    }
    float v = row[x0 < 0 ? 0 : WW - 1];
    return make_float2(v, v);
}

// bilinear sample of C planar channels at (gx,gy), border-clamped, float2 row taps
template<int C>
__device__ __forceinline__ void bilinN(const float* __restrict__ base,
                                       float gx, float gy, float out[C]) {
    const size_t plane = (size_t)HH * WW;
    float x0f = floorf(gx), y0f = floorf(gy);
    float ax = gx - x0f, ay = gy - y0f;
    int x0 = (int)x0f, y0 = (int)y0f;
    int y0i = min(max(y0, 0), HH - 1);
    int y1i = min(max(y0 + 1, 0), HH - 1);
    float w00 = (1.f - ay) * (1.f - ax), w01 = (1.f - ay) * ax;
    float w10 = ay * (1.f - ax), w11 = ay * ax;
#pragma unroll
    for (int c = 0; c < C; ++c) {
        const float* pl = base + c * plane;
        float2 r0 = ld2c(pl + (size_t)y0i * WW, x0);
        float2 r1 = ld2c(pl + (size_t)y1i * WW, x0);
        out[c] = w00 * r0.x + w01 * r0.y + w10 * r1.x + w11 * r1.y;
    }
}

// zero-padded read of one plane (matches jnp.pad zeros for the grad stencil)
__device__ __forceinline__ float ldz(const float* __restrict__ pl, int x, int y) {
    return ((unsigned)x < (unsigned)WW && (unsigned)y < (unsigned)HH)
         ? pl[(size_t)y * WW + x] : 0.f;
}

// Both directions in one dispatch: blockIdx.z = dir*BB + b
// __launch_bounds__(256) single-arg: max WG = 256 threads. WITHOUT this, hipcc
// budgets for 1024-thread WGs -> 64-VGPR clamp -> ~1.4 GB scratch spill (R2/R3).
__global__ __launch_bounds__(256)
void dir_kernel(const float* __restrict__ flowf, const float* __restrict__ flowb_,
                const float* __restrict__ img1, const float* __restrict__ img2,
                const float* __restrict__ target, float* __restrict__ acc) {
    __shared__ float lds_w[3][LW][LW];  // warped imgb (0 outside image = zero-pad)
    __shared__ float red[8];

    const int z = blockIdx.z;
    const int dir = z >> 3;
    const int b = z & 7;
    const float* flowa = dir ? flowb_ : flowf;
    const float* flowb = dir ? flowf : flowb_;
    const float* imga  = dir ? img2 : img1;
    const float* imgb  = dir ? img1 : img2;

    const int tx0 = blockIdx.x * TILE;
    const int ty0 = blockIdx.y * TILE;
    const int tid = threadIdx.x;
    const size_t plane = (size_t)HH * WW;
    const size_t fbase = (size_t)(b * 2) * plane;
    const size_t ibase = (size_t)(b * 3) * plane;

    // ---- halo phase: warp imgb by flowa into LDS ----
    for (int p = tid; p < LW * LW; p += 256) {
        int hy = p / LW, hx = p - hy * LW;
        int gy = ty0 + hy - HALO, gx = tx0 + hx - HALO;
        float w[3] = {0.f, 0.f, 0.f};
        if ((unsigned)gx < (unsigned)WW && (unsigned)gy < (unsigned)HH) {
            size_t fi = fbase + (size_t)gy * WW + gx;
            float fx = flowa[fi];
            float fy = flowa[fi + plane];
            bilinN<3>(imgb + ibase, (float)gx + fx, (float)gy + fy, w);
        }
        lds_w[0][hy][hx] = w[0];
        lds_w[1][hy][hx] = w[1];
        lds_w[2][hy][hx] = w[2];
    }
    __syncthreads();

    // ---- center phase ----
    float local = 0.f, lepe = 0.f;
    const float T0 = 1.f / 12.f, T1 = 2.f / 3.f;

#pragma unroll
    for (int i = 0; i < 4; ++i) {
        int p = i * 256 + tid;
        int ly = p >> 5, lx = p & 31;
        int y = ty0 + ly, x = tx0 + lx;

        size_t fi = fbase + (size_t)y * WW + x;
        float fx = flowa[fi], fy = flowa[fi + plane];
        float X = (float)x + fx, Y = (float)y + fy;

        // border mask
        float mask = sigm(X + 0.5f) * (1.f - sigm(X - ((float)WW - 0.5f)))
                   * sigm(Y + 0.5f) * (1.f - sigm(Y - ((float)HH - 0.5f)));

        // warped backward flow -> occlusion
        float wf[2];
        bilinN<2>(flowb + fbase, X, Y, wf);
        float mag = fx * fx + fy * fy + wf[0] * wf[0] + wf[1] * wf[1];
        float sx = fx + wf[0], sy = fy + wf[1];
        float d2 = sx * sx + sy * sy;
        float occ = 1.f - sigm(d2 - (0.01f * mag + 0.5f));
        mask *= occ;

        // data term (center only -> always in-image)
        float A = 0.f;
#pragma unroll
        for (int c = 0; c < 3; ++c) {
            float av = imga[ibase + c * plane + (size_t)y * WW + x];
            float d = av - lds_w[c][ly + 2][lx + 2];
            A += d * d;
        }

        // smooth term (forward diffs, zero at last col/row)
        float sm = 0.f;
        if (x < WW - 1) {
            float dfx = flowa[fi + 1] - fx;
            float dfy = flowa[fi + plane + 1] - fy;
            sm += dfx * dfx + dfy * dfy;
        }
        if (y < HH - 1) {
            float dfx = flowa[fi + WW] - fx;
            float dfy = flowa[fi + plane + WW] - fy;
            sm += dfx * dfx + dfy * dfy;
        }

        // gradient term: 5-tap derivatives; imga from global (zero-padded), warped from LDS
        float C = 0.f;
#pragma unroll
        for (int c = 0; c < 3; ++c) {
            const float* pl = imga + ibase + c * plane;
            float gha = T1 * (ldz(pl, x - 1, y) - ldz(pl, x + 1, y))
                      + T0 * (ldz(pl, x + 2, y) - ldz(pl, x - 2, y));
            float ghw = T1 * (lds_w[c][ly + 2][lx + 1] - lds_w[c][ly + 2][lx + 3])
                      + T0 * (lds_w[c][ly + 2][lx + 4] - lds_w[c][ly + 2][lx]);
            float d = gha - ghw;
            C += d * d;
            float gva = T1 * (ldz(pl, x, y - 1) - ldz(pl, x, y + 1))
                      + T0 * (ldz(pl, x, y + 2) - ldz(pl, x, y - 2));
            float gvw = T1 * (lds_w[c][ly + 1][lx + 2] - lds_w[c][ly + 3][lx + 2])
                      + T0 * (lds_w[c][ly + 4][lx + 2] - lds_w[c][ly][lx + 2]);
            d = gva - gvw;
            C += d * d;
        }

        local += sqrtf(A + 1e-5f) * mask             // ALPHA * data
               + sqrtf(sm + 1e-5f)                   // BETA * smooth
               + sqrtf(C + 1e-5f) * mask             // GAMMA * grad
               + 12.4f * (1.f - mask)                // MASK_COST * mask_term
               + sqrtf(d2 + 1e-5f) * mask;           // DELTA * fb contribution

        if (dir == 0) {
            float dx = fx - target[fi];
            float dy = fy - target[fi + plane];
            lepe += sqrtf(dx * dx + dy * dy);
        }
    }

    // ---- block reduction ----
#pragma unroll
    for (int off = 32; off > 0; off >>= 1) {
        local += __shfl_down(local, off);
        lepe  += __shfl_down(lepe, off);
    }
    int wid = tid >> 6;
    if ((tid & 63) == 0) { red[wid] = local; red[4 + wid] = lepe; }
    __syncthreads();
    if (tid == 0) {
        atomicAdd(&acc[0], red[0] + red[1] + red[2] + red[3]);
        if (dir == 0) atomicAdd(&acc[1], red[4] + red[5] + red[6] + red[7]);
    }
}

__global__ void finalize_kernel(const float* __restrict__ acc, float* __restrict__ out) {
    out[0] = acc[0] / (float)BB;
    out[1] = acc[1] / (float)((size_t)BB * HH * WW);
}

extern "C" void kernel_launch(void* const* d_in, const int* in_sizes, int n_in,
                              void* d_out, int out_size, void* d_ws, size_t ws_size,
                              hipStream_t stream) {
    const float* flowf  = (const float*)d_in[0];
    const float* flowb  = (const float*)d_in[1];
    const float* img1   = (const float*)d_in[2];
    const float* img2   = (const float*)d_in[3];
    const float* target = (const float*)d_in[4];
    float* out = (float*)d_out;
    float* acc = (float*)d_ws;

    hipMemsetAsync(acc, 0, 2 * sizeof(float), stream);

    dim3 grid(WW / TILE, HH / TILE, 2 * BB);
    dir_kernel<<<grid, 256, 0, stream>>>(flowf, flowb, img1, img2, target, acc);

    finalize_kernel<<<1, 1, 0, stream>>>(acc, out);
}

// Round 5
// 793.588 us; speedup vs baseline: 1.2677x; 1.2677x over previous
//
#include <hip/hip_runtime.h>

#define BB 8
#define HH 512
#define WW 1024
#define PLANE ((size_t)HH * WW)
#define TILE 32
#define HALO 2
#define LW (TILE + 2*HALO)   // 36

__device__ __forceinline__ float sigm(float v) { return 1.0f / (1.0f + __expf(-v)); }

// load (row[x0], row[x0+1]) with x clamped to [0, W-1]
__device__ __forceinline__ float2 ld2c(const float* __restrict__ row, int x0) {
    if ((unsigned)x0 < (unsigned)(WW - 1)) {
        return *reinterpret_cast<const float2*>(row + x0);
    }
    float v = row[x0 < 0 ? 0 : WW - 1];
    return make_float2(v, v);
}

// bilinear sample of C planar channels at (gx,gy), border-clamped, float2 row taps
template<int C>
__device__ __forceinline__ void bilinN(const float* __restrict__ base,
                                       float gx, float gy, float out[C]) {
    float x0f = floorf(gx), y0f = floorf(gy);
    float ax = gx - x0f, ay = gy - y0f;
    int x0 = (int)x0f, y0 = (int)y0f;
    int y0i = min(max(y0, 0), HH - 1);
    int y1i = min(max(y0 + 1, 0), HH - 1);
    float w00 = (1.f - ay) * (1.f - ax), w01 = (1.f - ay) * ax;
    float w10 = ay * (1.f - ax), w11 = ay * ax;
#pragma unroll
    for (int c = 0; c < C; ++c) {
        const float* pl = base + c * PLANE;
        float2 r0 = ld2c(pl + (size_t)y0i * WW, x0);
        float2 r1 = ld2c(pl + (size_t)y1i * WW, x0);
        out[c] = w00 * r0.x + w01 * r0.y + w10 * r1.x + w11 * r1.y;
    }
}

__device__ __forceinline__ void block_reduce_2(float a, float b, float* red,
                                               float* acc, int addB) {
    int tid = threadIdx.x;
#pragma unroll
    for (int off = 32; off > 0; off >>= 1) {
        a += __shfl_down(a, off);
        b += __shfl_down(b, off);
    }
    int wid = tid >> 6;
    if ((tid & 63) == 0) { red[wid] = a; red[4 + wid] = b; }
    __syncthreads();
    if (tid == 0) {
        atomicAdd(&acc[0], red[0] + red[1] + red[2] + red[3]);
        if (addB) atomicAdd(&acc[1], red[4] + red[5] + red[6] + red[7]);
    }
}

// ---- Pass 1: per-pixel warp + mask + data/smooth/fb/epe; writes e=imga-warped and mask ----
__global__ __launch_bounds__(256)
void pass1_kernel(const float* __restrict__ flowa, const float* __restrict__ flowb,
                  const float* __restrict__ imga, const float* __restrict__ imgb,
                  const float* __restrict__ target, float4* __restrict__ ebuf,
                  float* __restrict__ acc, int isFwd) {
    __shared__ float red[8];
    const int x = blockIdx.x * 256 + threadIdx.x;
    const int y = blockIdx.y;
    const int b = blockIdx.z;
    const size_t fbase = (size_t)(b * 2) * PLANE;
    const size_t ibase = (size_t)(b * 3) * PLANE;
    const size_t pi = (size_t)y * WW + x;

    const size_t fi = fbase + pi;
    float fx = flowa[fi], fy = flowa[fi + PLANE];
    float X = (float)x + fx, Y = (float)y + fy;

    // border mask
    float mask = sigm(X + 0.5f) * (1.f - sigm(X - ((float)WW - 0.5f)))
               * sigm(Y + 0.5f) * (1.f - sigm(Y - ((float)HH - 0.5f)));

    // warped opposite flow -> occlusion
    float wf[2];
    bilinN<2>(flowb + fbase, X, Y, wf);
    float mag = fx * fx + fy * fy + wf[0] * wf[0] + wf[1] * wf[1];
    float sx = fx + wf[0], sy = fy + wf[1];
    float d2 = sx * sx + sy * sy;
    mask *= 1.f - sigm(d2 - (0.01f * mag + 0.5f));

    // warp imgb, residual e = imga - warped
    float w[3];
    bilinN<3>(imgb + ibase, X, Y, w);
    float e0 = imga[ibase + pi] - w[0];
    float e1 = imga[ibase + PLANE + pi] - w[1];
    float e2 = imga[ibase + 2 * PLANE + pi] - w[2];
    float A = e0 * e0 + e1 * e1 + e2 * e2;

    // smooth term (forward diffs, zero at last col/row)
    float sm = 0.f;
    if (x < WW - 1) {
        float dx1 = flowa[fi + 1] - fx, dy1 = flowa[fi + PLANE + 1] - fy;
        sm += dx1 * dx1 + dy1 * dy1;
    }
    if (y < HH - 1) {
        float dx1 = flowa[fi + WW] - fx, dy1 = flowa[fi + PLANE + WW] - fy;
        sm += dx1 * dx1 + dy1 * dy1;
    }

    ebuf[(size_t)b * PLANE + pi] = make_float4(e0, e1, e2, mask);

    float local = sqrtf(A + 1e-5f) * mask        // ALPHA * data
                + sqrtf(sm + 1e-5f)              // BETA * smooth
                + 12.4f * (1.f - mask)           // MASK_COST * mask_term
                + sqrtf(d2 + 1e-5f) * mask;      // DELTA * fb
    float lepe = 0.f;
    if (isFwd) {
        float dx1 = fx - target[fi], dy1 = fy - target[fi + PLANE];
        lepe = sqrtf(dx1 * dx1 + dy1 * dy1);
    }
    block_reduce_2(local, lepe, red, acc, isFwd);
}

// ---- Pass 2: 5-point-cross stencil on e (zero-padded), adds GAMMA*sqrt(C)*mask ----
__global__ __launch_bounds__(256)
void pass2_kernel(const float4* __restrict__ ebuf, float* __restrict__ acc) {
    __shared__ float4 t[LW][LW];   // 20.7 KB
    __shared__ float red[8];
    const int tx0 = blockIdx.x * TILE, ty0 = blockIdx.y * TILE;
    const int b = blockIdx.z;
    const float4* pb = ebuf + (size_t)b * PLANE;

    for (int p = threadIdx.x; p < LW * LW; p += 256) {
        int hy = p / LW, hx = p - hy * LW;
        int gy = ty0 + hy - HALO, gx = tx0 + hx - HALO;
        float4 v = make_float4(0.f, 0.f, 0.f, 0.f);
        if ((unsigned)gx < (unsigned)WW && (unsigned)gy < (unsigned)HH)
            v = pb[(size_t)gy * WW + gx];
        t[hy][hx] = v;
    }
    __syncthreads();

    float local = 0.f;
    const float T0 = 1.f / 12.f, T1 = 2.f / 3.f;
#pragma unroll
    for (int i = 0; i < 4; ++i) {
        int p = i * 256 + threadIdx.x;
        int ly = p >> 5, lx = p & 31;
        float4 hL1 = t[ly + 2][lx + 1], hR1 = t[ly + 2][lx + 3];
        float4 hL2 = t[ly + 2][lx],     hR2 = t[ly + 2][lx + 4];
        float4 vU1 = t[ly + 1][lx + 2], vD1 = t[ly + 3][lx + 2];
        float4 vU2 = t[ly][lx + 2],     vD2 = t[ly + 4][lx + 2];
        float C = 0.f, gh, gv;
        gh = T1 * (hL1.x - hR1.x) + T0 * (hR2.x - hL2.x);
        gv = T1 * (vU1.x - vD1.x) + T0 * (vD2.x - vU2.x);
        C += gh * gh + gv * gv;
        gh = T1 * (hL1.y - hR1.y) + T0 * (hR2.y - hL2.y);
        gv = T1 * (vU1.y - vD1.y) + T0 * (vD2.y - vU2.y);
        C += gh * gh + gv * gv;
        gh = T1 * (hL1.z - hR1.z) + T0 * (hR2.z - hL2.z);
        gv = T1 * (vU1.z - vD1.z) + T0 * (vD2.z - vU2.z);
        C += gh * gh + gv * gv;
        local += sqrtf(C + 1e-5f) * t[ly + 2][lx + 2].w;
    }
    block_reduce_2(local, 0.f, red, acc, 0);
}

// ---- Fallback (exact R1 structure, proven 364 us) if ws is too small ----
template<bool EPE>
__global__ __launch_bounds__(256)
void dir_kernel_fb(const float* __restrict__ flowa, const float* __restrict__ flowb,
                   const float* __restrict__ imga, const float* __restrict__ imgb,
                   const float* __restrict__ target, float* __restrict__ acc) {
    __shared__ float lds_w[3][LW][LW];
    __shared__ float lds_a[3][LW][LW];
    __shared__ float red[8];
    const int b = blockIdx.z;
    const int tx0 = blockIdx.x * TILE, ty0 = blockIdx.y * TILE;
    const int tid = threadIdx.x;
    const size_t fbase = (size_t)(b * 2) * PLANE;
    const size_t ibase = (size_t)(b * 3) * PLANE;

    for (int p = tid; p < LW * LW; p += 256) {
        int hy = p / LW, hx = p - hy * LW;
        int gy = ty0 + hy - HALO, gx = tx0 + hx - HALO;
        float w[3] = {0.f, 0.f, 0.f};
        float a0 = 0.f, a1 = 0.f, a2 = 0.f;
        if ((unsigned)gx < (unsigned)WW && (unsigned)gy < (unsigned)HH) {
            size_t fi = fbase + (size_t)gy * WW + gx;
            bilinN<3>(imgb + ibase, (float)gx + flowa[fi], (float)gy + flowa[fi + PLANE], w);
            size_t ii = ibase + (size_t)gy * WW + gx;
            a0 = imga[ii]; a1 = imga[ii + PLANE]; a2 = imga[ii + 2 * PLANE];
        }
        lds_w[0][hy][hx] = w[0]; lds_w[1][hy][hx] = w[1]; lds_w[2][hy][hx] = w[2];
        lds_a[0][hy][hx] = a0;   lds_a[1][hy][hx] = a1;   lds_a[2][hy][hx] = a2;
    }
    __syncthreads();

    float local = 0.f, lepe = 0.f;
    const float T0 = 1.f / 12.f, T1 = 2.f / 3.f;
#pragma unroll
    for (int i = 0; i < 4; ++i) {
        int p = i * 256 + tid;
        int ly = p >> 5, lx = p & 31;
        int y = ty0 + ly, x = tx0 + lx;
        size_t fi = fbase + (size_t)y * WW + x;
        float fx = flowa[fi], fy = flowa[fi + PLANE];
        float X = (float)x + fx, Y = (float)y + fy;
        float mask = sigm(X + 0.5f) * (1.f - sigm(X - ((float)WW - 0.5f)))
                   * sigm(Y + 0.5f) * (1.f - sigm(Y - ((float)HH - 0.5f)));
        float wf[2];
        bilinN<2>(flowb + fbase, X, Y, wf);
        float mag = fx * fx + fy * fy + wf[0] * wf[0] + wf[1] * wf[1];
        float sx = fx + wf[0], sy = fy + wf[1];
        float d2 = sx * sx + sy * sy;
        mask *= 1.f - sigm(d2 - (0.01f * mag + 0.5f));
        float A = 0.f;
#pragma unroll
        for (int c = 0; c < 3; ++c) {
            float d = lds_a[c][ly + 2][lx + 2] - lds_w[c][ly + 2][lx + 2];
            A += d * d;
        }
        float sm = 0.f;
        if (x < WW - 1) {
            float dfx = flowa[fi + 1] - fx, dfy = flowa[fi + PLANE + 1] - fy;
            sm += dfx * dfx + dfy * dfy;
        }
        if (y < HH - 1) {
            float dfx = flowa[fi + WW] - fx, dfy = flowa[fi + PLANE + WW] - fy;
            sm += dfx * dfx + dfy * dfy;
        }
        float C = 0.f;
#pragma unroll
        for (int c = 0; c < 3; ++c) {
            float gha = T1 * (lds_a[c][ly + 2][lx + 1] - lds_a[c][ly + 2][lx + 3])
                      + T0 * (lds_a[c][ly + 2][lx + 4] - lds_a[c][ly + 2][lx]);
            float ghw = T1 * (lds_w[c][ly + 2][lx + 1] - lds_w[c][ly + 2][lx + 3])
                      + T0 * (lds_w[c][ly + 2][lx + 4] - lds_w[c][ly + 2][lx]);
            float d = gha - ghw; C += d * d;
            float gva = T1 * (lds_a[c][ly + 1][lx + 2] - lds_a[c][ly + 3][lx + 2])
                      + T0 * (lds_a[c][ly + 4][lx + 2] - lds_a[c][ly][lx + 2]);
            float gvw = T1 * (lds_w[c][ly + 1][lx + 2] - lds_w[c][ly + 3][lx + 2])
                      + T0 * (lds_w[c][ly + 4][lx + 2] - lds_w[c][ly][lx + 2]);
            d = gva - gvw; C += d * d;
        }
        local += sqrtf(A + 1e-5f) * mask + sqrtf(sm + 1e-5f)
               + sqrtf(C + 1e-5f) * mask + 12.4f * (1.f - mask)
               + sqrtf(d2 + 1e-5f) * mask;
        if (EPE) {
            float dx1 = fx - target[fi], dy1 = fy - target[fi + PLANE];
            lepe += sqrtf(dx1 * dx1 + dy1 * dy1);
        }
    }
    block_reduce_2(local, lepe, red, acc, EPE ? 1 : 0);
}

__global__ void finalize_kernel(const float* __restrict__ acc, float* __restrict__ out) {
    out[0] = acc[0] / (float)BB;
    out[1] = acc[1] / (float)((size_t)BB * HH * WW);
}

extern "C" void kernel_launch(void* const* d_in, const int* in_sizes, int n_in,
                              void* d_out, int out_size, void* d_ws, size_t ws_size,
                              hipStream_t stream) {
    const float* flowf  = (const float*)d_in[0];
    const float* flowb  = (const float*)d_in[1];
    const float* img1   = (const float*)d_in[2];
    const float* img2   = (const float*)d_in[3];
    const float* target = (const float*)d_in[4];
    float* out = (float*)d_out;
    float* acc = (float*)d_ws;

    hipMemsetAsync(acc, 0, 16, stream);

    const size_t need = 16 + (size_t)BB * PLANE * sizeof(float4);   // ~67 MB
    if (ws_size >= need) {
        float4* ebuf = (float4*)((char*)d_ws + 16);
        dim3 g1(WW / 256, HH, BB);
        dim3 g2(WW / TILE, HH / TILE, BB);
        // forward direction
        pass1_kernel<<<g1, 256, 0, stream>>>(flowf, flowb, img1, img2, target, ebuf, acc, 1);
        pass2_kernel<<<g2, 256, 0, stream>>>(ebuf, acc);
        // backward direction (reuses ebuf)
        pass1_kernel<<<g1, 256, 0, stream>>>(flowb, flowf, img2, img1, nullptr, ebuf, acc, 0);
        pass2_kernel<<<g2, 256, 0, stream>>>(ebuf, acc);
    } else {
        dim3 grid(WW / TILE, HH / TILE, BB);
        dir_kernel_fb<true ><<<grid, 256, 0, stream>>>(flowf, flowb, img1, img2, target, acc);
        dir_kernel_fb<false><<<grid, 256, 0, stream>>>(flowb, flowf, img2, img1, nullptr, acc);
    }

    finalize_kernel<<<1, 1, 0, stream>>>(acc, out);
}

// Round 6
// 790.543 us; speedup vs baseline: 1.2725x; 1.0039x over previous
//
#include <hip/hip_runtime.h>

#define BB 8
#define HH 512
#define WW 1024
#define PLANE ((size_t)HH * WW)
#define TILE 32
#define HALO 2
#define LW (TILE + 2*HALO)   // 36

__device__ __forceinline__ float sigm(float v) { return 1.0f / (1.0f + __expf(-v)); }

// load (row[x0], row[x0+1]) with x clamped to [0, W-1]
__device__ __forceinline__ float2 ld2c(const float* __restrict__ row, int x0) {
    if ((unsigned)x0 < (unsigned)(WW - 1)) {
        return *reinterpret_cast<const float2*>(row + x0);
    }
    float v = row[x0 < 0 ? 0 : WW - 1];
    return make_float2(v, v);
}

// bilinear sample of C planar channels at (gx,gy), border-clamped, float2 row taps
template<int C>
__device__ __forceinline__ void bilinN(const float* __restrict__ base,
                                       float gx, float gy, float out[C]) {
    float x0f = floorf(gx), y0f = floorf(gy);
    float ax = gx - x0f, ay = gy - y0f;
    int x0 = (int)x0f, y0 = (int)y0f;
    int y0i = min(max(y0, 0), HH - 1);
    int y1i = min(max(y0 + 1, 0), HH - 1);
    float w00 = (1.f - ay) * (1.f - ax), w01 = (1.f - ay) * ax;
    float w10 = ay * (1.f - ax), w11 = ay * ax;
#pragma unroll
    for (int c = 0; c < C; ++c) {
        const float* pl = base + c * PLANE;
        float2 r0 = ld2c(pl + (size_t)y0i * WW, x0);
        float2 r1 = ld2c(pl + (size_t)y1i * WW, x0);
        out[c] = w00 * r0.x + w01 * r0.y + w10 * r1.x + w11 * r1.y;
    }
}

__device__ __forceinline__ void block_reduce_2(float a, float b, float* red,
                                               float* acc, int addB) {
    int tid = threadIdx.x;
#pragma unroll
    for (int off = 32; off > 0; off >>= 1) {
        a += __shfl_down(a, off);
        b += __shfl_down(b, off);
    }
    int wid = tid >> 6;
    if ((tid & 63) == 0) { red[wid] = a; red[4 + wid] = b; }
    __syncthreads();
    if (tid == 0) {
        atomicAdd(&acc[0], red[0] + red[1] + red[2] + red[3]);
        if (addB) atomicAdd(&acc[1], red[4] + red[5] + red[6] + red[7]);
    }
}

// ---- Pass 1: per-pixel warp + mask + data/smooth/fb/epe; writes e=imga-warped and mask ----
// (256,4): 128-VGPR budget. Single-arg bounds gave VGPR=32 -> zero MLP -> 439us (R5).
__global__ __launch_bounds__(256, 4)
void pass1_kernel(const float* __restrict__ flowa, const float* __restrict__ flowb,
                  const float* __restrict__ imga, const float* __restrict__ imgb,
                  const float* __restrict__ target, float4* __restrict__ ebuf,
                  float* __restrict__ acc, int isFwd) {
    __shared__ float red[8];
    const int x = blockIdx.x * 256 + threadIdx.x;
    const int y = blockIdx.y;
    const int b = blockIdx.z;
    const size_t fbase = (size_t)(b * 2) * PLANE;
    const size_t ibase = (size_t)(b * 3) * PLANE;
    const size_t pi = (size_t)y * WW + x;
    const size_t fi = fbase + pi;

    // ---- batch 1: all flow-independent loads (issue together) ----
    float fx = flowa[fi];
    float fy = flowa[fi + PLANE];
    float a0 = imga[ibase + pi];
    float a1 = imga[ibase + PLANE + pi];
    float a2 = imga[ibase + 2 * PLANE + pi];
    // neighbor flows via clamped (always in-bounds) indices; masked later by select
    const int xr = min(x + 1, WW - 1);
    const int yd = min(y + 1, HH - 1);
    const size_t fir = fbase + (size_t)y * WW + xr;
    const size_t fid = fbase + (size_t)yd * WW + x;
    float nfxr = flowa[fir], nfyr = flowa[fir + PLANE];
    float nfxd = flowa[fid], nfyd = flowa[fid + PLANE];
    float tx = 0.f, ty = 0.f;
    if (isFwd) { tx = target[fi]; ty = target[fi + PLANE]; }

    // ---- batch 2: all gathers (depend only on fx,fy) ----
    float X = (float)x + fx, Y = (float)y + fy;
    float wf[2];
    bilinN<2>(flowb + fbase, X, Y, wf);
    float w[3];
    bilinN<3>(imgb + ibase, X, Y, w);

    // ---- compute phase ----
    float mask = sigm(X + 0.5f) * (1.f - sigm(X - ((float)WW - 0.5f)))
               * sigm(Y + 0.5f) * (1.f - sigm(Y - ((float)HH - 0.5f)));
    float mag = fx * fx + fy * fy + wf[0] * wf[0] + wf[1] * wf[1];
    float sx = fx + wf[0], sy = fy + wf[1];
    float d2 = sx * sx + sy * sy;
    mask *= 1.f - sigm(d2 - (0.01f * mag + 0.5f));

    float e0 = a0 - w[0], e1 = a1 - w[1], e2 = a2 - w[2];
    float A = e0 * e0 + e1 * e1 + e2 * e2;

    float dxr = nfxr - fx, dyr = nfyr - fy;
    float dxd = nfxd - fx, dyd = nfyd - fy;
    float smr = (x < WW - 1) ? (dxr * dxr + dyr * dyr) : 0.f;
    float smd = (y < HH - 1) ? (dxd * dxd + dyd * dyd) : 0.f;
    float sm = smr + smd;

    ebuf[(size_t)b * PLANE + pi] = make_float4(e0, e1, e2, mask);

    float local = sqrtf(A + 1e-5f) * mask        // ALPHA * data
                + sqrtf(sm + 1e-5f)              // BETA * smooth
                + 12.4f * (1.f - mask)           // MASK_COST * mask_term
                + sqrtf(d2 + 1e-5f) * mask;      // DELTA * fb
    float lepe = 0.f;
    if (isFwd) {
        float dx1 = fx - tx, dy1 = fy - ty;
        lepe = sqrtf(dx1 * dx1 + dy1 * dy1);
    }
    block_reduce_2(local, lepe, red, acc, isFwd);
}

// ---- Pass 2: 5-point-cross stencil on e (zero-padded), adds GAMMA*sqrt(C)*mask ----
__global__ __launch_bounds__(256, 4)
void pass2_kernel(const float4* __restrict__ ebuf, float* __restrict__ acc) {
    __shared__ float4 t[LW][LW];   // 20.7 KB
    __shared__ float red[8];
    const int tx0 = blockIdx.x * TILE, ty0 = blockIdx.y * TILE;
    const int b = blockIdx.z;
    const float4* pb = ebuf + (size_t)b * PLANE;

    for (int p = threadIdx.x; p < LW * LW; p += 256) {
        int hy = p / LW, hx = p - hy * LW;
        int gy = ty0 + hy - HALO, gx = tx0 + hx - HALO;
        float4 v = make_float4(0.f, 0.f, 0.f, 0.f);
        if ((unsigned)gx < (unsigned)WW && (unsigned)gy < (unsigned)HH)
            v = pb[(size_t)gy * WW + gx];
        t[hy][hx] = v;
    }
    __syncthreads();

    float local = 0.f;
    const float T0 = 1.f / 12.f, T1 = 2.f / 3.f;
#pragma unroll
    for (int i = 0; i < 4; ++i) {
        int p = i * 256 + threadIdx.x;
        int ly = p >> 5, lx = p & 31;
        float4 hL1 = t[ly + 2][lx + 1], hR1 = t[ly + 2][lx + 3];
        float4 hL2 = t[ly + 2][lx],     hR2 = t[ly + 2][lx + 4];
        float4 vU1 = t[ly + 1][lx + 2], vD1 = t[ly + 3][lx + 2];
        float4 vU2 = t[ly][lx + 2],     vD2 = t[ly + 4][lx + 2];
        float C = 0.f, gh, gv;
        gh = T1 * (hL1.x - hR1.x) + T0 * (hR2.x - hL2.x);
        gv = T1 * (vU1.x - vD1.x) + T0 * (vD2.x - vU2.x);
        C += gh * gh + gv * gv;
        gh = T1 * (hL1.y - hR1.y) + T0 * (hR2.y - hL2.y);
        gv = T1 * (vU1.y - vD1.y) + T0 * (vD2.y - vU2.y);
        C += gh * gh + gv * gv;
        gh = T1 * (hL1.z - hR1.z) + T0 * (hR2.z - hL2.z);
        gv = T1 * (vU1.z - vD1.z) + T0 * (vD2.z - vU2.z);
        C += gh * gh + gv * gv;
        local += sqrtf(C + 1e-5f) * t[ly + 2][lx + 2].w;
    }
    block_reduce_2(local, 0.f, red, acc, 0);
}

// ---- Fallback (R1 structure) if ws is too small ----
template<bool EPE>
__global__ __launch_bounds__(256)
void dir_kernel_fb(const float* __restrict__ flowa, const float* __restrict__ flowb,
                   const float* __restrict__ imga, const float* __restrict__ imgb,
                   const float* __restrict__ target, float* __restrict__ acc) {
    __shared__ float lds_w[3][LW][LW];
    __shared__ float lds_a[3][LW][LW];
    __shared__ float red[8];
    const int b = blockIdx.z;
    const int tx0 = blockIdx.x * TILE, ty0 = blockIdx.y * TILE;
    const int tid = threadIdx.x;
    const size_t fbase = (size_t)(b * 2) * PLANE;
    const size_t ibase = (size_t)(b * 3) * PLANE;

    for (int p = tid; p < LW * LW; p += 256) {
        int hy = p / LW, hx = p - hy * LW;
        int gy = ty0 + hy - HALO, gx = tx0 + hx - HALO;
        float w[3] = {0.f, 0.f, 0.f};
        float a0 = 0.f, a1 = 0.f, a2 = 0.f;
        if ((unsigned)gx < (unsigned)WW && (unsigned)gy < (unsigned)HH) {
            size_t fi = fbase + (size_t)gy * WW + gx;
            bilinN<3>(imgb + ibase, (float)gx + flowa[fi], (float)gy + flowa[fi + PLANE], w);
            size_t ii = ibase + (size_t)gy * WW + gx;
            a0 = imga[ii]; a1 = imga[ii + PLANE]; a2 = imga[ii + 2 * PLANE];
        }
        lds_w[0][hy][hx] = w[0]; lds_w[1][hy][hx] = w[1]; lds_w[2][hy][hx] = w[2];
        lds_a[0][hy][hx] = a0;   lds_a[1][hy][hx] = a1;   lds_a[2][hy][hx] = a2;
    }
    __syncthreads();

    float local = 0.f, lepe = 0.f;
    const float T0 = 1.f / 12.f, T1 = 2.f / 3.f;
#pragma unroll
    for (int i = 0; i < 4; ++i) {
        int p = i * 256 + tid;
        int ly = p >> 5, lx = p & 31;
        int y = ty0 + ly, x = tx0 + lx;
        size_t fi = fbase + (size_t)y * WW + x;
        float fx = flowa[fi], fy = flowa[fi + PLANE];
        float X = (float)x + fx, Y = (float)y + fy;
        float mask = sigm(X + 0.5f) * (1.f - sigm(X - ((float)WW - 0.5f)))
                   * sigm(Y + 0.5f) * (1.f - sigm(Y - ((float)HH - 0.5f)));
        float wf[2];
        bilinN<2>(flowb + fbase, X, Y, wf);
        float mag = fx * fx + fy * fy + wf[0] * wf[0] + wf[1] * wf[1];
        float sx = fx + wf[0], sy = fy + wf[1];
        float d2 = sx * sx + sy * sy;
        mask *= 1.f - sigm(d2 - (0.01f * mag + 0.5f));
        float A = 0.f;
#pragma unroll
        for (int c = 0; c < 3; ++c) {
            float d = lds_a[c][ly + 2][lx + 2] - lds_w[c][ly + 2][lx + 2];
            A += d * d;
        }
        float sm = 0.f;
        if (x < WW - 1) {
            float dfx = flowa[fi + 1] - fx, dfy = flowa[fi + PLANE + 1] - fy;
            sm += dfx * dfx + dfy * dfy;
        }
        if (y < HH - 1) {
            float dfx = flowa[fi + WW] - fx, dfy = flowa[fi + PLANE + WW] - fy;
            sm += dfx * dfx + dfy * dfy;
        }
        float C = 0.f;
#pragma unroll
        for (int c = 0; c < 3; ++c) {
            float gha = T1 * (lds_a[c][ly + 2][lx + 1] - lds_a[c][ly + 2][lx + 3])
                      + T0 * (lds_a[c][ly + 2][lx + 4] - lds_a[c][ly + 2][lx]);
            float ghw = T1 * (lds_w[c][ly + 2][lx + 1] - lds_w[c][ly + 2][lx + 3])
                      + T0 * (lds_w[c][ly + 2][lx + 4] - lds_w[c][ly + 2][lx]);
            float d = gha - ghw; C += d * d;
            float gva = T1 * (lds_a[c][ly + 1][lx + 2] - lds_a[c][ly + 3][lx + 2])
                      + T0 * (lds_a[c][ly + 4][lx + 2] - lds_a[c][ly][lx + 2]);
            float gvw = T1 * (lds_w[c][ly + 1][lx + 2] - lds_w[c][ly + 3][lx + 2])
                      + T0 * (lds_w[c][ly + 4][lx + 2] - lds_w[c][ly][lx + 2]);
            d = gva - gvw; C += d * d;
        }
        local += sqrtf(A + 1e-5f) * mask + sqrtf(sm + 1e-5f)
               + sqrtf(C + 1e-5f) * mask + 12.4f * (1.f - mask)
               + sqrtf(d2 + 1e-5f) * mask;
        if (EPE) {
            float dx1 = fx - target[fi], dy1 = fy - target[fi + PLANE];
            lepe += sqrtf(dx1 * dx1 + dy1 * dy1);
        }
    }
    block_reduce_2(local, lepe, red, acc, EPE ? 1 : 0);
}

__global__ void finalize_kernel(const float* __restrict__ acc, float* __restrict__ out) {
    out[0] = acc[0] / (float)BB;
    out[1] = acc[1] / (float)((size_t)BB * HH * WW);
}

extern "C" void kernel_launch(void* const* d_in, const int* in_sizes, int n_in,
                              void* d_out, int out_size, void* d_ws, size_t ws_size,
                              hipStream_t stream) {
    const float* flowf  = (const float*)d_in[0];
    const float* flowb  = (const float*)d_in[1];
    const float* img1   = (const float*)d_in[2];
    const float* img2   = (const float*)d_in[3];
    const float* target = (const float*)d_in[4];
    float* out = (float*)d_out;
    float* acc = (float*)d_ws;

    hipMemsetAsync(acc, 0, 16, stream);

    const size_t need = 16 + (size_t)BB * PLANE * sizeof(float4);   // ~67 MB
    if (ws_size >= need) {
        float4* ebuf = (float4*)((char*)d_ws + 16);
        dim3 g1(WW / 256, HH, BB);
        dim3 g2(WW / TILE, HH / TILE, BB);
        // forward direction
        pass1_kernel<<<g1, 256, 0, stream>>>(flowf, flowb, img1, img2, target, ebuf, acc, 1);
        pass2_kernel<<<g2, 256, 0, stream>>>(ebuf, acc);
        // backward direction (reuses ebuf)
        pass1_kernel<<<g1, 256, 0, stream>>>(flowb, flowf, img2, img1, nullptr, ebuf, acc, 0);
        pass2_kernel<<<g2, 256, 0, stream>>>(ebuf, acc);
    } else {
        dim3 grid(WW / TILE, HH / TILE, BB);
        dir_kernel_fb<true ><<<grid, 256, 0, stream>>>(flowf, flowb, img1, img2, target, acc);
        dir_kernel_fb<false><<<grid, 256, 0, stream>>>(flowb, flowf, img2, img1, nullptr, acc);
    }

    finalize_kernel<<<1, 1, 0, stream>>>(acc, out);
}

// Round 7
// 527.228 us; speedup vs baseline: 1.9081x; 1.4994x over previous
//
#include <hip/hip_runtime.h>

#define BB 8
#define HH 512
#define WW 1024
#define PLANE ((size_t)HH * WW)
#define TILE 32
#define HALO 2
#define LW (TILE + 2*HALO)   // 36
// gather staging window: tile +/- 16 px
#define GH 16
#define SW 64
#define SP 68                // padded stride: 16B-aligned rows, banks rotate by 4/row

__device__ __forceinline__ float sigm(float v) { return 1.0f / (1.0f + __expf(-v)); }

// ---------- legacy global-gather helpers (fallback paths) ----------
__device__ __forceinline__ float2 ld2c(const float* __restrict__ row, int x0) {
    if ((unsigned)x0 < (unsigned)(WW - 1)) {
        return *reinterpret_cast<const float2*>(row + x0);
    }
    float v = row[x0 < 0 ? 0 : WW - 1];
    return make_float2(v, v);
}

template<int C>
__device__ __forceinline__ void bilinN(const float* __restrict__ base,
                                       float gx, float gy, float out[C]) {
    float x0f = floorf(gx), y0f = floorf(gy);
    float ax = gx - x0f, ay = gy - y0f;
    int x0 = (int)x0f, y0 = (int)y0f;
    int y0i = min(max(y0, 0), HH - 1);
    int y1i = min(max(y0 + 1, 0), HH - 1);
    float w00 = (1.f - ay) * (1.f - ax), w01 = (1.f - ay) * ax;
    float w10 = ay * (1.f - ax), w11 = ay * ax;
#pragma unroll
    for (int c = 0; c < C; ++c) {
        const float* pl = base + c * PLANE;
        float2 r0 = ld2c(pl + (size_t)y0i * WW, x0);
        float2 r1 = ld2c(pl + (size_t)y1i * WW, x0);
        out[c] = w00 * r0.x + w01 * r0.y + w10 * r1.x + w11 * r1.y;
    }
}

__device__ __forceinline__ void block_reduce_2(float a, float b, float* red,
                                               float* acc, int addB) {
    int tid = threadIdx.x;
#pragma unroll
    for (int off = 32; off > 0; off >>= 1) {
        a += __shfl_down(a, off);
        b += __shfl_down(b, off);
    }
    int wid = tid >> 6;
    if ((tid & 63) == 0) { red[wid] = a; red[4 + wid] = b; }
    __syncthreads();
    if (tid == 0) {
        atomicAdd(&acc[0], red[0] + red[1] + red[2] + red[3]);
        if (addB) atomicAdd(&acc[1], red[4] + red[5] + red[6] + red[7]);
    }
}

// ---------- LDS staging of one plane's 64x64 window around the tile ----------
__device__ __forceinline__ void stage_plane(const float* __restrict__ pl,
                                            float (* __restrict__ st)[SP],
                                            int tx0, int ty0, bool interior) {
    const int tid = threadIdx.x;
    const int sy = tid >> 2;            // 0..63
    const int sx0 = (tid & 3) << 4;     // 0,16,32,48
    if (interior) {
        const float* src = pl + (size_t)(ty0 - GH + sy) * WW + (tx0 - GH + sx0);
        float4 v0 = ((const float4*)src)[0];
        float4 v1 = ((const float4*)src)[1];
        float4 v2 = ((const float4*)src)[2];
        float4 v3 = ((const float4*)src)[3];
        float4* dst = (float4*)&st[sy][sx0];
        dst[0] = v0; dst[1] = v1; dst[2] = v2; dst[3] = v3;
    } else {
        int gy = min(max(ty0 - GH + sy, 0), HH - 1);
        const float* row = pl + (size_t)gy * WW;
#pragma unroll
        for (int k = 0; k < 16; ++k) {
            int gx = min(max(tx0 - GH + sx0 + k, 0), WW - 1);
            st[sy][sx0 + k] = row[gx];
        }
    }
}

// bilinear gather of one plane from the staged window; rare out-of-window lanes
// fall back to a border-clamped global gather.
__device__ __forceinline__ float gather1(const float (* __restrict__ st)[SP],
                                         const float* __restrict__ pl,
                                         float X, float Y, int tx0, int ty0) {
    float x0f = floorf(X), y0f = floorf(Y);
    float ax = X - x0f, ay = Y - y0f;
    int x0 = (int)x0f, y0 = (int)y0f;
    int sx = x0 - (tx0 - GH);
    int sy = y0 - (ty0 - GH);
    float v00, v01, v10, v11;
    if ((unsigned)sx < (unsigned)(SW - 1) && (unsigned)sy < (unsigned)(SW - 1)) {
        v00 = st[sy][sx];     v01 = st[sy][sx + 1];
        v10 = st[sy + 1][sx]; v11 = st[sy + 1][sx + 1];
    } else {
        int x0i = min(max(x0, 0), WW - 1), x1i = min(max(x0 + 1, 0), WW - 1);
        int y0i = min(max(y0, 0), HH - 1), y1i = min(max(y0 + 1, 0), HH - 1);
        v00 = pl[(size_t)y0i * WW + x0i]; v01 = pl[(size_t)y0i * WW + x1i];
        v10 = pl[(size_t)y1i * WW + x0i]; v11 = pl[(size_t)y1i * WW + x1i];
    }
    return (1.f - ay) * ((1.f - ax) * v00 + ax * v01)
         + ay * ((1.f - ax) * v10 + ax * v11);
}

// ---- Pass 1: LDS-staged gathers. 32x32 tile, 256 threads, 4 px/thread. ----
__global__ __launch_bounds__(256)
void pass1_kernel(const float* __restrict__ flowa, const float* __restrict__ flowb,
                  const float* __restrict__ imga, const float* __restrict__ imgb,
                  const float* __restrict__ target, float4* __restrict__ ebuf,
                  float* __restrict__ acc, int isFwd) {
    __shared__ float st[SW][SP];   // 17.4 KB, reused across 5 phases
    __shared__ float red[8];

    const int tid = threadIdx.x;
    const int bx = blockIdx.x, by = blockIdx.y, b = blockIdx.z;
    const int tx0 = bx * TILE, ty0 = by * TILE;
    const bool interior = (bx >= 1 && bx <= (WW / TILE - 2) && by >= 1 && by <= (HH / TILE - 2));
    const size_t fbase = (size_t)(b * 2) * PLANE;
    const size_t ibase = (size_t)(b * 3) * PLANE;

    const float* fbx = flowb + fbase;          // flowb x-plane
    const float* fby = flowb + fbase + PLANE;  // flowb y-plane

    float fx4[4], fy4[4], mask4[4], wfx4[4];
    float e04[4], e14[4], e24[4];
    float local = 0.f, lepe = 0.f;

    // ---- phase 0: stage flowb-x; meanwhile coalesced own/neighbor/target loads ----
    stage_plane(fbx, st, tx0, ty0, interior);
#pragma unroll
    for (int i = 0; i < 4; ++i) {
        int p = i * 256 + tid;
        int ly = p >> 5, lx = p & 31;
        int x = tx0 + lx, y = ty0 + ly;
        size_t fi = fbase + (size_t)y * WW + x;
        float fx = flowa[fi], fy = flowa[fi + PLANE];
        fx4[i] = fx; fy4[i] = fy;
        // smooth term (coalesced neighbor loads, clamped then masked)
        int xr = min(x + 1, WW - 1), yd = min(y + 1, HH - 1);
        size_t fir = fbase + (size_t)y * WW + xr;
        size_t fid = fbase + (size_t)yd * WW + x;
        float dxr = flowa[fir] - fx, dyr = flowa[fir + PLANE] - fy;
        float dxd = flowa[fid] - fx, dyd = flowa[fid + PLANE] - fy;
        float sm = ((x < WW - 1) ? (dxr * dxr + dyr * dyr) : 0.f)
                 + ((y < HH - 1) ? (dxd * dxd + dyd * dyd) : 0.f);
        local += sqrtf(sm + 1e-5f);
        if (isFwd) {
            float tx = target[fi], ty = target[fi + PLANE];
            float dx1 = fx - tx, dy1 = fy - ty;
            lepe += sqrtf(dx1 * dx1 + dy1 * dy1);
        }
        // border mask (flow-only part)
        float X = (float)x + fx, Y = (float)y + fy;
        mask4[i] = sigm(X + 0.5f) * (1.f - sigm(X - ((float)WW - 0.5f)))
                 * sigm(Y + 0.5f) * (1.f - sigm(Y - ((float)HH - 0.5f)));
    }
    __syncthreads();
#pragma unroll
    for (int i = 0; i < 4; ++i) {
        int p = i * 256 + tid;
        int x = tx0 + (p & 31), y = ty0 + (p >> 5);
        wfx4[i] = gather1(st, fbx, (float)x + fx4[i], (float)y + fy4[i], tx0, ty0);
    }
    __syncthreads();

    // ---- phase 1: stage flowb-y; gather wfy; finish mask/occ/fb ----
    stage_plane(fby, st, tx0, ty0, interior);
    __syncthreads();
#pragma unroll
    for (int i = 0; i < 4; ++i) {
        int p = i * 256 + tid;
        int x = tx0 + (p & 31), y = ty0 + (p >> 5);
        float fx = fx4[i], fy = fy4[i];
        float wfy = gather1(st, fby, (float)x + fx, (float)y + fy, tx0, ty0);
        float wfx = wfx4[i];
        float mag = fx * fx + fy * fy + wfx * wfx + wfy * wfy;
        float sx = fx + wfx, sy = fy + wfy;
        float d2 = sx * sx + sy * sy;
        float mask = mask4[i] * (1.f - sigm(d2 - (0.01f * mag + 0.5f)));
        mask4[i] = mask;
        local += 12.4f * (1.f - mask)            // MASK_COST
               + sqrtf(d2 + 1e-5f) * mask;       // DELTA * fb
    }
    __syncthreads();

    // ---- phases 2..4: stage imgb channel c; gather; e_c = imga_c - warped ----
#pragma unroll
    for (int c = 0; c < 3; ++c) {
        const float* pl = imgb + ibase + c * PLANE;
        stage_plane(pl, st, tx0, ty0, interior);
        const float* apl = imga + ibase + c * PLANE;
        float a4[4];
#pragma unroll
        for (int i = 0; i < 4; ++i) {
            int p = i * 256 + tid;
            a4[i] = apl[(size_t)(ty0 + (p >> 5)) * WW + (tx0 + (p & 31))];
        }
        __syncthreads();
#pragma unroll
        for (int i = 0; i < 4; ++i) {
            int p = i * 256 + tid;
            int x = tx0 + (p & 31), y = ty0 + (p >> 5);
            float w = gather1(st, pl, (float)x + fx4[i], (float)y + fy4[i], tx0, ty0);
            float e = a4[i] - w;
            if (c == 0) e04[i] = e; else if (c == 1) e14[i] = e; else e24[i] = e;
        }
        if (c < 2) __syncthreads();
    }

    // ---- epilogue: data term + ebuf store ----
#pragma unroll
    for (int i = 0; i < 4; ++i) {
        int p = i * 256 + tid;
        int x = tx0 + (p & 31), y = ty0 + (p >> 5);
        float A = e04[i] * e04[i] + e14[i] * e14[i] + e24[i] * e24[i];
        local += sqrtf(A + 1e-5f) * mask4[i];
        ebuf[(size_t)b * PLANE + (size_t)y * WW + x] =
            make_float4(e04[i], e14[i], e24[i], mask4[i]);
    }

    block_reduce_2(local, lepe, red, acc, isFwd);
}

// ---- Pass 2: 5-point-cross stencil on e (zero-padded), adds GAMMA*sqrt(C)*mask ----
__global__ __launch_bounds__(256, 4)
void pass2_kernel(const float4* __restrict__ ebuf, float* __restrict__ acc) {
    __shared__ float4 t[LW][LW];   // 20.7 KB
    __shared__ float red[8];
    const int tx0 = blockIdx.x * TILE, ty0 = blockIdx.y * TILE;
    const int b = blockIdx.z;
    const float4* pb = ebuf + (size_t)b * PLANE;

    for (int p = threadIdx.x; p < LW * LW; p += 256) {
        int hy = p / LW, hx = p - hy * LW;
        int gy = ty0 + hy - HALO, gx = tx0 + hx - HALO;
        float4 v = make_float4(0.f, 0.f, 0.f, 0.f);
        if ((unsigned)gx < (unsigned)WW && (unsigned)gy < (unsigned)HH)
            v = pb[(size_t)gy * WW + gx];
        t[hy][hx] = v;
    }
    __syncthreads();

    float local = 0.f;
    const float T0 = 1.f / 12.f, T1 = 2.f / 3.f;
#pragma unroll
    for (int i = 0; i < 4; ++i) {
        int p = i * 256 + threadIdx.x;
        int ly = p >> 5, lx = p & 31;
        float4 hL1 = t[ly + 2][lx + 1], hR1 = t[ly + 2][lx + 3];
        float4 hL2 = t[ly + 2][lx],     hR2 = t[ly + 2][lx + 4];
        float4 vU1 = t[ly + 1][lx + 2], vD1 = t[ly + 3][lx + 2];
        float4 vU2 = t[ly][lx + 2],     vD2 = t[ly + 4][lx + 2];
        float C = 0.f, gh, gv;
        gh = T1 * (hL1.x - hR1.x) + T0 * (hR2.x - hL2.x);
        gv = T1 * (vU1.x - vD1.x) + T0 * (vD2.x - vU2.x);
        C += gh * gh + gv * gv;
        gh = T1 * (hL1.y - hR1.y) + T0 * (hR2.y - hL2.y);
        gv = T1 * (vU1.y - vD1.y) + T0 * (vD2.y - vU2.y);
        C += gh * gh + gv * gv;
        gh = T1 * (hL1.z - hR1.z) + T0 * (hR2.z - hL2.z);
        gv = T1 * (vU1.z - vD1.z) + T0 * (vD2.z - vU2.z);
        C += gh * gh + gv * gv;
        local += sqrtf(C + 1e-5f) * t[ly + 2][lx + 2].w;
    }
    block_reduce_2(local, 0.f, red, acc, 0);
}

// ---- Fallback (R1 structure) if ws is too small ----
template<bool EPE>
__global__ __launch_bounds__(256)
void dir_kernel_fb(const float* __restrict__ flowa, const float* __restrict__ flowb,
                   const float* __restrict__ imga, const float* __restrict__ imgb,
                   const float* __restrict__ target, float* __restrict__ acc) {
    __shared__ float lds_w[3][LW][LW];
    __shared__ float lds_a[3][LW][LW];
    __shared__ float red[8];
    const int b = blockIdx.z;
    const int tx0 = blockIdx.x * TILE, ty0 = blockIdx.y * TILE;
    const int tid = threadIdx.x;
    const size_t fbase = (size_t)(b * 2) * PLANE;
    const size_t ibase = (size_t)(b * 3) * PLANE;

    for (int p = tid; p < LW * LW; p += 256) {
        int hy = p / LW, hx = p - hy * LW;
        int gy = ty0 + hy - HALO, gx = tx0 + hx - HALO;
        float w[3] = {0.f, 0.f, 0.f};
        float a0 = 0.f, a1 = 0.f, a2 = 0.f;
        if ((unsigned)gx < (unsigned)WW && (unsigned)gy < (unsigned)HH) {
            size_t fi = fbase + (size_t)gy * WW + gx;
            bilinN<3>(imgb + ibase, (float)gx + flowa[fi], (float)gy + flowa[fi + PLANE], w);
            size_t ii = ibase + (size_t)gy * WW + gx;
            a0 = imga[ii]; a1 = imga[ii + PLANE]; a2 = imga[ii + 2 * PLANE];
        }
        lds_w[0][hy][hx] = w[0]; lds_w[1][hy][hx] = w[1]; lds_w[2][hy][hx] = w[2];
        lds_a[0][hy][hx] = a0;   lds_a[1][hy][hx] = a1;   lds_a[2][hy][hx] = a2;
    }
    __syncthreads();

    float local = 0.f, lepe = 0.f;
    const float T0 = 1.f / 12.f, T1 = 2.f / 3.f;
#pragma unroll
    for (int i = 0; i < 4; ++i) {
        int p = i * 256 + tid;
        int ly = p >> 5, lx = p & 31;
        int y = ty0 + ly, x = tx0 + lx;
        size_t fi = fbase + (size_t)y * WW + x;
        float fx = flowa[fi], fy = flowa[fi + PLANE];
        float X = (float)x + fx, Y = (float)y + fy;
        float mask = sigm(X + 0.5f) * (1.f - sigm(X - ((float)WW - 0.5f)))
                   * sigm(Y + 0.5f) * (1.f - sigm(Y - ((float)HH - 0.5f)));
        float wf[2];
        bilinN<2>(flowb + fbase, X, Y, wf);
        float mag = fx * fx + fy * fy + wf[0] * wf[0] + wf[1] * wf[1];
        float sx = fx + wf[0], sy = fy + wf[1];
        float d2 = sx * sx + sy * sy;
        mask *= 1.f - sigm(d2 - (0.01f * mag + 0.5f));
        float A = 0.f;
#pragma unroll
        for (int c = 0; c < 3; ++c) {
            float d = lds_a[c][ly + 2][lx + 2] - lds_w[c][ly + 2][lx + 2];
            A += d * d;
        }
        float sm = 0.f;
        if (x < WW - 1) {
            float dfx = flowa[fi + 1] - fx, dfy = flowa[fi + PLANE + 1] - fy;
            sm += dfx * dfx + dfy * dfy;
        }
        if (y < HH - 1) {
            float dfx = flowa[fi + WW] - fx, dfy = flowa[fi + PLANE + WW] - fy;
            sm += dfx * dfx + dfy * dfy;
        }
        float C = 0.f;
#pragma unroll
        for (int c = 0; c < 3; ++c) {
            float gha = T1 * (lds_a[c][ly + 2][lx + 1] - lds_a[c][ly + 2][lx + 3])
                      + T0 * (lds_a[c][ly + 2][lx + 4] - lds_a[c][ly + 2][lx]);
            float ghw = T1 * (lds_w[c][ly + 2][lx + 1] - lds_w[c][ly + 2][lx + 3])
                      + T0 * (lds_w[c][ly + 2][lx + 4] - lds_w[c][ly + 2][lx]);
            float d = gha - ghw; C += d * d;
            float gva = T1 * (lds_a[c][ly + 1][lx + 2] - lds_a[c][ly + 3][lx + 2])
                      + T0 * (lds_a[c][ly + 4][lx + 2] - lds_a[c][ly][lx + 2]);
            float gvw = T1 * (lds_w[c][ly + 1][lx + 2] - lds_w[c][ly + 3][lx + 2])
                      + T0 * (lds_w[c][ly + 4][lx + 2] - lds_w[c][ly][lx + 2]);
            d = gva - gvw; C += d * d;
        }
        local += sqrtf(A + 1e-5f) * mask + sqrtf(sm + 1e-5f)
               + sqrtf(C + 1e-5f) * mask + 12.4f * (1.f - mask)
               + sqrtf(d2 + 1e-5f) * mask;
        if (EPE) {
            float dx1 = fx - target[fi], dy1 = fy - target[fi + PLANE];
            lepe += sqrtf(dx1 * dx1 + dy1 * dy1);
        }
    }
    block_reduce_2(local, lepe, red, acc, EPE ? 1 : 0);
}

__global__ void finalize_kernel(const float* __restrict__ acc, float* __restrict__ out) {
    out[0] = acc[0] / (float)BB;
    out[1] = acc[1] / (float)((size_t)BB * HH * WW);
}

extern "C" void kernel_launch(void* const* d_in, const int* in_sizes, int n_in,
                              void* d_out, int out_size, void* d_ws, size_t ws_size,
                              hipStream_t stream) {
    const float* flowf  = (const float*)d_in[0];
    const float* flowb  = (const float*)d_in[1];
    const float* img1   = (const float*)d_in[2];
    const float* img2   = (const float*)d_in[3];
    const float* target = (const float*)d_in[4];
    float* out = (float*)d_out;
    float* acc = (float*)d_ws;

    hipMemsetAsync(acc, 0, 16, stream);

    const size_t need = 16 + (size_t)BB * PLANE * sizeof(float4);   // ~67 MB
    if (ws_size >= need) {
        float4* ebuf = (float4*)((char*)d_ws + 16);
        dim3 g1(WW / TILE, HH / TILE, BB);
        dim3 g2(WW / TILE, HH / TILE, BB);
        // forward direction
        pass1_kernel<<<g1, 256, 0, stream>>>(flowf, flowb, img1, img2, target, ebuf, acc, 1);
        pass2_kernel<<<g2, 256, 0, stream>>>(ebuf, acc);
        // backward direction (reuses ebuf)
        pass1_kernel<<<g1, 256, 0, stream>>>(flowb, flowf, img2, img1, nullptr, ebuf, acc, 0);
        pass2_kernel<<<g2, 256, 0, stream>>>(ebuf, acc);
    } else {
        dim3 grid(WW / TILE, HH / TILE, BB);
        dir_kernel_fb<true ><<<grid, 256, 0, stream>>>(flowf, flowb, img1, img2, target, acc);
        dir_kernel_fb<false><<<grid, 256, 0, stream>>>(flowb, flowf, img2, img1, nullptr, acc);
    }

    finalize_kernel<<<1, 1, 0, stream>>>(acc, out);
}